// Round 9
// baseline (321.954 us; speedup 1.0000x reference)
//
#include <hip/hip_runtime.h>
#include <hip/hip_fp16.h>

#define RES 512
#define NCH 32
#define HW (RES * RES)
#define PLANE_H_ELEMS (NCH * HW)     // half elements per transposed plane
#define NBUCKETS 4096                // 16x16x16 Morton voxel grid

// ---------------------------------------------------------------------------
// Morton bucket helpers
// ---------------------------------------------------------------------------
__device__ __forceinline__ unsigned spread3(unsigned x) {
    x &= 0x3FF;
    x = (x | (x << 16)) & 0x030000FF;
    x = (x | (x <<  8)) & 0x0300F00F;
    x = (x | (x <<  4)) & 0x030C30C3;
    x = (x | (x <<  2)) & 0x09249249;
    return x;
}
__device__ __forceinline__ unsigned bucket_of(float c0, float c1, float c2) {
    int bx = min(max((int)(c0 * 16.f), 0), 15);
    int by = min(max((int)(c1 * 16.f), 0), 15);
    int bz = min(max((int)(c2 * 16.f), 0), 15);
    return spread3(bx) | (spread3(by) << 1) | (spread3(bz) << 2);
}

// ---------------------------------------------------------------------------
// Tiny zero kernel for the histogram.
// ---------------------------------------------------------------------------
__global__ __launch_bounds__(256) void zero_hist(unsigned* __restrict__ hist) {
    hist[blockIdx.x * 256 + threadIdx.x] = 0u;
}

// ---------------------------------------------------------------------------
// Pre-pass: transpose (C,H,W) fp32 -> (H,W,C) fp16. LDS-tiled, coalesced.
// (verbatim from the passing round-7 kernel)
// ---------------------------------------------------------------------------
__global__ __launch_bounds__(256) void transpose_chw_hwc_h(
    const float* __restrict__ p0, const float* __restrict__ p1,
    const float* __restrict__ p2, __half2* __restrict__ dst_all)
{
    __shared__ float lds[64 * 33];
    int blk   = blockIdx.x;
    int t     = threadIdx.x;
    int plane = blk >> 12;
    int rem   = blk & 4095;
    int y     = rem >> 3;
    int xt    = (rem & 7) << 6;
    const float* src = (plane == 0) ? p0 : (plane == 1) ? p1 : p2;
    __half2* dst = dst_all + (size_t)plane * (PLANE_H_ELEMS / 2);

    #pragma unroll
    for (int k = 0; k < 8; ++k) {
        int idx = t + (k << 8);      // 0..2047
        int c   = idx >> 6;          // channel 0..31
        int xi  = idx & 63;          // x within tile
        lds[xi * 33 + c] = src[(size_t)c * HW + (size_t)y * RES + xt + xi];
    }
    __syncthreads();
    #pragma unroll
    for (int k = 0; k < 4; ++k) {
        int idx = t + (k << 8);      // 0..1023
        int xi  = idx >> 4;          // x within tile
        int cp  = idx & 15;          // channel pair
        __half2 h = __halves2half2(__float2half_rn(lds[xi * 33 + 2 * cp]),
                                   __float2half_rn(lds[xi * 33 + 2 * cp + 1]));
        dst[((size_t)(y * RES + xt + xi)) * 16 + cp] = h;
    }
}

// ---------------------------------------------------------------------------
// Counting sort pass 1: per-block LDS histogram -> global histogram.
// ---------------------------------------------------------------------------
__global__ __launch_bounds__(256) void hist_kernel(
    const float* __restrict__ x, int npts, unsigned* __restrict__ hist)
{
    __shared__ unsigned lh[NBUCKETS];
    int t = threadIdx.x;
    for (int i = t; i < NBUCKETS; i += 256) lh[i] = 0;
    __syncthreads();

    int per = (npts + gridDim.x - 1) / gridDim.x;
    int start = blockIdx.x * per;
    int end = min(npts, start + per);
    for (int i = start + t; i < end; i += 256) {
        float c0 = x[3 * i + 0], c1 = x[3 * i + 1], c2 = x[3 * i + 2];
        atomicAdd(&lh[bucket_of(c0, c1, c2)], 1u);
    }
    __syncthreads();
    for (int i = t; i < NBUCKETS; i += 256)
        if (lh[i]) atomicAdd(&hist[i], lh[i]);
}

// ---------------------------------------------------------------------------
// Counting sort pass 2: exclusive scan of 4096 counts. One block, 1024 thr.
// ---------------------------------------------------------------------------
__global__ __launch_bounds__(1024) void scan_kernel(
    const unsigned* __restrict__ hist, unsigned* __restrict__ offs)
{
    __shared__ unsigned sd[1024];
    int t = threadIdx.x;
    unsigned h0 = hist[4 * t + 0], h1 = hist[4 * t + 1];
    unsigned h2 = hist[4 * t + 2], h3 = hist[4 * t + 3];
    sd[t] = h0 + h1 + h2 + h3;
    __syncthreads();
    for (int d = 1; d < 1024; d <<= 1) {
        unsigned v = (t >= d) ? sd[t - d] : 0u;
        __syncthreads();
        sd[t] += v;
        __syncthreads();
    }
    unsigned excl = (t > 0) ? sd[t - 1] : 0u;
    offs[4 * t + 0] = excl;
    offs[4 * t + 1] = excl + h0;
    offs[4 * t + 2] = excl + h0 + h1;
    offs[4 * t + 3] = excl + h0 + h1 + h2;
}

// ---------------------------------------------------------------------------
// Counting sort pass 3: scatter (c0,c1,c2,orig_idx) into bucket order.
// ---------------------------------------------------------------------------
__global__ __launch_bounds__(256) void scatter_kernel(
    const float* __restrict__ x, int npts, unsigned* __restrict__ offs,
    float4* __restrict__ sorted)
{
    int i = blockIdx.x * 256 + threadIdx.x;
    if (i >= npts) return;
    float c0 = x[3 * i + 0], c1 = x[3 * i + 1], c2 = x[3 * i + 2];
    unsigned b = bucket_of(c0, c1, c2);
    unsigned pos = atomicAdd(&offs[b], 1u);
    sorted[pos] = make_float4(c0, c1, c2, __int_as_float(i));
}

// ---------------------------------------------------------------------------
// Main sampler (r7 body, single change: PLAIN out store instead of
// nontemporal). 8 lanes per point, lane q owns channels [4q,4q+4) (proven
// uint2 decode). MLP restructure: all addresses+weights first, then all 12
// corner gathers back-to-back, then math. __launch_bounds__(256,4) allows
// up to 128 VGPR so the loads stay in flight.
// Store rationale: plain float4 stores let 8 lanes' 128B coalesce into
// write-back L2 lines; NT streamed 16B quanta past L2 (suspected partial-
// line HBM writes -- this round bisects that).
// ---------------------------------------------------------------------------
__global__ __launch_bounds__(256, 4) void sample_sorted_h(
    const float4* __restrict__ sorted, const __half* __restrict__ planes,
    float* __restrict__ out, int npts, int nb_q, int nb_r)
{
    int bid = blockIdx.x;
    int xcd = bid & 7;
    int j   = bid >> 3;
    int chunk = (xcd < nb_r ? xcd * (nb_q + 1) : nb_r * (nb_q + 1) + (xcd - nb_r) * nb_q) + j;

    int s = chunk * 32 + (threadIdx.x >> 3);   // sorted-point index
    int q = threadIdx.x & 7;                   // channel quad
    if (s >= npts) return;

    float4 p = sorted[s];
    int b = __float_as_int(p.w);               // original point index

    const float gxs[3] = { p.x, p.x, p.y };
    const float gys[3] = { p.y, p.z, p.z };

    // Phase 1: addresses + weights for all three planes (no loads yet).
    const __half* base[3];
    float w00[3], w01[3], w10[3], w11[3];
    #pragma unroll
    for (int pl = 0; pl < 3; ++pl) {
        float ix = fmaf(gxs[pl], 255.5f, 255.5f);
        float iy = fmaf(gys[pl], 255.5f, 255.5f);
        float xf = floorf(ix), yf = floorf(iy);
        float wx = ix - xf,  wy = iy - yf;
        int x0 = min(max((int)xf, 0), RES - 2);
        int y0 = min(max((int)yf, 0), RES - 2);
        base[pl] = planes + (size_t)pl * PLANE_H_ELEMS
                 + (size_t)(y0 * RES + x0) * NCH + q * 4;
        float omx = 1.f - wx, omy = 1.f - wy;
        w00[pl] = omx * omy; w01[pl] = wx * omy;
        w10[pl] = omx * wy;  w11[pl] = wx * wy;
    }

    // Phase 2: issue all 12 corner gathers back-to-back (MLP).
    uint2 u00[3], u01[3], u10[3], u11[3];
    #pragma unroll
    for (int pl = 0; pl < 3; ++pl) {
        u00[pl] = *(const uint2*)(base[pl]);
        u01[pl] = *(const uint2*)(base[pl] + NCH);
        u10[pl] = *(const uint2*)(base[pl] + RES * NCH);
        u11[pl] = *(const uint2*)(base[pl] + RES * NCH + NCH);
    }

    // Phase 3: decode + interpolate (proven r5/r7 math).
    float4 acc = make_float4(1.f, 1.f, 1.f, 1.f);
    #pragma unroll
    for (int pl = 0; pl < 3; ++pl) {
        float2 a00 = __half22float2(__builtin_bit_cast(__half2, u00[pl].x));
        float2 b00 = __half22float2(__builtin_bit_cast(__half2, u00[pl].y));
        float2 a01 = __half22float2(__builtin_bit_cast(__half2, u01[pl].x));
        float2 b01 = __half22float2(__builtin_bit_cast(__half2, u01[pl].y));
        float2 a10 = __half22float2(__builtin_bit_cast(__half2, u10[pl].x));
        float2 b10 = __half22float2(__builtin_bit_cast(__half2, u10[pl].y));
        float2 a11 = __half22float2(__builtin_bit_cast(__half2, u11[pl].x));
        float2 b11 = __half22float2(__builtin_bit_cast(__half2, u11[pl].y));

        float4 f;
        f.x = fmaf(a00.x, w00[pl], fmaf(a01.x, w01[pl], fmaf(a10.x, w10[pl], a11.x * w11[pl])));
        f.y = fmaf(a00.y, w00[pl], fmaf(a01.y, w01[pl], fmaf(a10.y, w10[pl], a11.y * w11[pl])));
        f.z = fmaf(b00.x, w00[pl], fmaf(b01.x, w01[pl], fmaf(b10.x, w10[pl], b11.x * w11[pl])));
        f.w = fmaf(b00.y, w00[pl], fmaf(b01.y, w01[pl], fmaf(b10.y, w10[pl], b11.y * w11[pl])));

        acc.x *= f.x; acc.y *= f.y; acc.z *= f.z; acc.w *= f.w;
    }

    *(float4*)(out + (size_t)b * NCH + q * 4) = acc;   // plain write-back store
}

// ---------------------------------------------------------------------------
// Fallback if d_ws is too small: sample directly from (C,H,W) fp32.
// ---------------------------------------------------------------------------
__global__ __launch_bounds__(256) void triplane_sample_chw(
    const float* __restrict__ x, const float* __restrict__ p0,
    const float* __restrict__ p1, const float* __restrict__ p2,
    float* __restrict__ out, int npts)
{
    int gid = blockIdx.x * 256 + threadIdx.x;
    int b = gid >> 5;
    int c = gid & 31;
    if (b >= npts) return;

    float c0 = x[b * 3 + 0], c1 = x[b * 3 + 1], c2 = x[b * 3 + 2];
    const float gxs[3] = { c0, c0, c1 };
    const float gys[3] = { c1, c2, c2 };
    const float* planes[3] = { p0, p1, p2 };

    float acc = 1.f;
    #pragma unroll
    for (int pl = 0; pl < 3; ++pl) {
        float ix = fmaf(gxs[pl], 255.5f, 255.5f);
        float iy = fmaf(gys[pl], 255.5f, 255.5f);
        float xf = floorf(ix), yf = floorf(iy);
        float wx = ix - xf,  wy = iy - yf;
        int x0 = min(max((int)xf, 0), RES - 2);
        int y0 = min(max((int)yf, 0), RES - 2);

        const float* base = planes[pl] + (size_t)c * HW + (size_t)y0 * RES + x0;
        float v00 = base[0], v01 = base[1], v10 = base[RES], v11 = base[RES + 1];

        float omx = 1.f - wx, omy = 1.f - wy;
        acc *= fmaf(v00, omx * omy, fmaf(v01, wx * omy,
               fmaf(v10, omx * wy, v11 * (wx * wy))));
    }
    out[(size_t)b * NCH + c] = acc;
}

extern "C" void kernel_launch(void* const* d_in, const int* in_sizes, int n_in,
                              void* d_out, int out_size, void* d_ws, size_t ws_size,
                              hipStream_t stream) {
    const float* x  = (const float*)d_in[0];
    const float* p0 = (const float*)d_in[1];
    const float* p1 = (const float*)d_in[2];
    const float* p2 = (const float*)d_in[3];
    float* out = (float*)d_out;
    int npts = in_sizes[0] / 3;

    // workspace layout
    size_t planes_bytes = (size_t)3 * PLANE_H_ELEMS * sizeof(__half);   // 50.3 MB
    size_t sorted_bytes = (size_t)npts * sizeof(float4);                // 32 MB
    size_t hist_bytes   = NBUCKETS * sizeof(unsigned);
    size_t need = planes_bytes + sorted_bytes + 2 * hist_bytes;

    if (ws_size >= need) {
        char* ws = (char*)d_ws;
        __half*   planes_h = (__half*)ws;
        float4*   sorted   = (float4*)(ws + planes_bytes);
        unsigned* hist     = (unsigned*)(ws + planes_bytes + sorted_bytes);
        unsigned* offs     = hist + NBUCKETS;

        zero_hist<<<NBUCKETS / 256, 256, 0, stream>>>(hist);
        transpose_chw_hwc_h<<<3 * 4096, 256, 0, stream>>>(p0, p1, p2,
                                                          (__half2*)planes_h);
        hist_kernel<<<256, 256, 0, stream>>>(x, npts, hist);
        scan_kernel<<<1, 1024, 0, stream>>>(hist, offs);
        scatter_kernel<<<(npts + 255) / 256, 256, 0, stream>>>(x, npts, offs, sorted);

        int nchunks = (npts + 31) / 32;       // 32 points per block
        int nb_q = nchunks / 8, nb_r = nchunks & 7;
        sample_sorted_h<<<nchunks, 256, 0, stream>>>(sorted, planes_h, out, npts, nb_q, nb_r);
    } else {
        long long nthreads = (long long)npts * 32;
        int blocks = (int)((nthreads + 255) / 256);
        triplane_sample_chw<<<blocks, 256, 0, stream>>>(x, p0, p1, p2, out, npts);
    }
}

// Round 10
// 291.638 us; speedup vs baseline: 1.1040x; 1.1040x over previous
//
#include <hip/hip_runtime.h>
#include <hip/hip_fp16.h>

#define RES 512
#define NCH 32
#define HW (RES * RES)
#define PLANE_H_ELEMS (NCH * HW)     // half elements per transposed plane
#define NBUCKETS 4096                // 16x16x16 Morton voxel grid

typedef float vfloat4 __attribute__((ext_vector_type(4)));  // proven for NT STORE only

// ---------------------------------------------------------------------------
// Morton bucket helpers
// ---------------------------------------------------------------------------
__device__ __forceinline__ unsigned spread3(unsigned x) {
    x &= 0x3FF;
    x = (x | (x << 16)) & 0x030000FF;
    x = (x | (x <<  8)) & 0x0300F00F;
    x = (x | (x <<  4)) & 0x030C30C3;
    x = (x | (x <<  2)) & 0x09249249;
    return x;
}
__device__ __forceinline__ unsigned bucket_of(float c0, float c1, float c2) {
    int bx = min(max((int)(c0 * 16.f), 0), 15);
    int by = min(max((int)(c1 * 16.f), 0), 15);
    int bz = min(max((int)(c2 * 16.f), 0), 15);
    return spread3(bx) | (spread3(by) << 1) | (spread3(bz) << 2);
}

// ---------------------------------------------------------------------------
// Pre-pass: transpose (C,H,W) fp32 -> (H,W,C) fp16, LDS-tiled, coalesced.
// Blocks 0..15 also zero the 4096-entry histogram (stream-ordered before
// hist_kernel, so this is race-free; saves a graph node).
// ---------------------------------------------------------------------------
__global__ __launch_bounds__(256) void transpose_chw_hwc_h(
    const float* __restrict__ p0, const float* __restrict__ p1,
    const float* __restrict__ p2, __half2* __restrict__ dst_all,
    unsigned* __restrict__ hist)
{
    __shared__ float lds[64 * 33];
    int blk   = blockIdx.x;
    int t     = threadIdx.x;
    if (blk < 16) hist[blk * 256 + t] = 0u;

    int plane = blk >> 12;
    int rem   = blk & 4095;
    int y     = rem >> 3;
    int xt    = (rem & 7) << 6;
    const float* src = (plane == 0) ? p0 : (plane == 1) ? p1 : p2;
    __half2* dst = dst_all + (size_t)plane * (PLANE_H_ELEMS / 2);

    #pragma unroll
    for (int k = 0; k < 8; ++k) {
        int idx = t + (k << 8);      // 0..2047
        int c   = idx >> 6;          // channel 0..31
        int xi  = idx & 63;          // x within tile
        lds[xi * 33 + c] = src[(size_t)c * HW + (size_t)y * RES + xt + xi];
    }
    __syncthreads();
    #pragma unroll
    for (int k = 0; k < 4; ++k) {
        int idx = t + (k << 8);      // 0..1023
        int xi  = idx >> 4;          // x within tile
        int cp  = idx & 15;          // channel pair
        __half2 h = __halves2half2(__float2half_rn(lds[xi * 33 + 2 * cp]),
                                   __float2half_rn(lds[xi * 33 + 2 * cp + 1]));
        dst[((size_t)(y * RES + xt + xi)) * 16 + cp] = h;
    }
}

// ---------------------------------------------------------------------------
// Counting sort pass 1: per-block LDS histogram -> global histogram.
// ---------------------------------------------------------------------------
__global__ __launch_bounds__(256) void hist_kernel(
    const float* __restrict__ x, int npts, unsigned* __restrict__ hist)
{
    __shared__ unsigned lh[NBUCKETS];
    int t = threadIdx.x;
    for (int i = t; i < NBUCKETS; i += 256) lh[i] = 0;
    __syncthreads();

    int per = (npts + gridDim.x - 1) / gridDim.x;
    int start = blockIdx.x * per;
    int end = min(npts, start + per);
    for (int i = start + t; i < end; i += 256) {
        float c0 = x[3 * i + 0], c1 = x[3 * i + 1], c2 = x[3 * i + 2];
        atomicAdd(&lh[bucket_of(c0, c1, c2)], 1u);
    }
    __syncthreads();
    for (int i = t; i < NBUCKETS; i += 256)
        if (lh[i]) atomicAdd(&hist[i], lh[i]);
}

// ---------------------------------------------------------------------------
// Counting sort pass 2: exclusive scan of 4096 counts. One block, 1024 thr.
// ---------------------------------------------------------------------------
__global__ __launch_bounds__(1024) void scan_kernel(
    const unsigned* __restrict__ hist, unsigned* __restrict__ offs)
{
    __shared__ unsigned sd[1024];
    int t = threadIdx.x;
    unsigned h0 = hist[4 * t + 0], h1 = hist[4 * t + 1];
    unsigned h2 = hist[4 * t + 2], h3 = hist[4 * t + 3];
    sd[t] = h0 + h1 + h2 + h3;
    __syncthreads();
    for (int d = 1; d < 1024; d <<= 1) {
        unsigned v = (t >= d) ? sd[t - d] : 0u;
        __syncthreads();
        sd[t] += v;
        __syncthreads();
    }
    unsigned excl = (t > 0) ? sd[t - 1] : 0u;
    offs[4 * t + 0] = excl;
    offs[4 * t + 1] = excl + h0;
    offs[4 * t + 2] = excl + h0 + h1;
    offs[4 * t + 3] = excl + h0 + h1 + h2;
}

// ---------------------------------------------------------------------------
// Counting sort pass 3: scatter (c0,c1,c2,orig_idx) into bucket order.
// ---------------------------------------------------------------------------
__global__ __launch_bounds__(256) void scatter_kernel(
    const float* __restrict__ x, int npts, unsigned* __restrict__ offs,
    float4* __restrict__ sorted)
{
    int i = blockIdx.x * 256 + threadIdx.x;
    if (i >= npts) return;
    float c0 = x[3 * i + 0], c1 = x[3 * i + 1], c2 = x[3 * i + 2];
    unsigned b = bucket_of(c0, c1, c2);
    unsigned pos = atomicAdd(&offs[b], 1u);
    sorted[pos] = make_float4(c0, c1, c2, __int_as_float(i));
}

// ---------------------------------------------------------------------------
// fp16-pair decode + bilinear accumulate helper (proven math path).
// ---------------------------------------------------------------------------
__device__ __forceinline__ float2 dec2(unsigned u) {
    return __half22float2(__builtin_bit_cast(__half2, u));
}
__device__ __forceinline__ void bilerp2(float2& acc, unsigned c00, unsigned c01,
                                        unsigned c10, unsigned c11,
                                        float w00, float w01, float w10, float w11) {
    float2 a = dec2(c00), b = dec2(c01), c = dec2(c10), d = dec2(c11);
    float f0 = fmaf(a.x, w00, fmaf(b.x, w01, fmaf(c.x, w10, d.x * w11)));
    float f1 = fmaf(a.y, w00, fmaf(b.y, w01, fmaf(c.y, w10, d.y * w11)));
    acc.x *= f0; acc.y *= f1;
}

// ---------------------------------------------------------------------------
// Main sampler: 4 lanes per point; lane q owns channels [8q,8q+8).
// Corner loads are uint4 HIP-struct (dwordx4) -- NOT ext_vector derefs (the
// r3/r4 miscompile construct); float4-struct 16B loads are proven (sorted).
// MLP: addresses+weights for all planes first, then all 12 gathers
// back-to-back, then math. NT ext-vector STORE (proven r7/r8) keeps the
// 256MB scattered output from evicting planes out of L2.
// ---------------------------------------------------------------------------
__global__ __launch_bounds__(256, 4) void sample_sorted_u4(
    const float4* __restrict__ sorted, const __half* __restrict__ planes,
    float* __restrict__ out, int npts, int nb_q, int nb_r)
{
    int bid = blockIdx.x;
    int xcd = bid & 7;
    int j   = bid >> 3;
    int chunk = (xcd < nb_r ? xcd * (nb_q + 1) : nb_r * (nb_q + 1) + (xcd - nb_r) * nb_q) + j;

    int s = chunk * 64 + (threadIdx.x >> 2);   // 64 points per block
    int q = threadIdx.x & 3;                   // channel octet
    if (s >= npts) return;

    float4 p = sorted[s];
    int b = __float_as_int(p.w);               // original point index

    const float gxs[3] = { p.x, p.x, p.y };
    const float gys[3] = { p.y, p.z, p.z };

    // Phase 1: addresses + weights for all three planes (no loads yet).
    const __half* base[3];
    float w00[3], w01[3], w10[3], w11[3];
    #pragma unroll
    for (int pl = 0; pl < 3; ++pl) {
        float ix = fmaf(gxs[pl], 255.5f, 255.5f);
        float iy = fmaf(gys[pl], 255.5f, 255.5f);
        float xf = floorf(ix), yf = floorf(iy);
        float wx = ix - xf,  wy = iy - yf;
        int x0 = min(max((int)xf, 0), RES - 2);
        int y0 = min(max((int)yf, 0), RES - 2);
        base[pl] = planes + (size_t)pl * PLANE_H_ELEMS
                 + (size_t)(y0 * RES + x0) * NCH + q * 8;
        float omx = 1.f - wx, omy = 1.f - wy;
        w00[pl] = omx * omy; w01[pl] = wx * omy;
        w10[pl] = omx * wy;  w11[pl] = wx * wy;
    }

    // Phase 2: issue all 12 corner gathers back-to-back (dwordx4 each).
    uint4 u00[3], u01[3], u10[3], u11[3];
    #pragma unroll
    for (int pl = 0; pl < 3; ++pl) {
        u00[pl] = *(const uint4*)(base[pl]);
        u01[pl] = *(const uint4*)(base[pl] + NCH);
        u10[pl] = *(const uint4*)(base[pl] + RES * NCH);
        u11[pl] = *(const uint4*)(base[pl] + RES * NCH + NCH);
    }

    // Phase 3: decode + interpolate 8 channels (4 half2 pairs).
    float2 acc0 = {1.f, 1.f}, acc1 = {1.f, 1.f}, acc2 = {1.f, 1.f}, acc3 = {1.f, 1.f};
    #pragma unroll
    for (int pl = 0; pl < 3; ++pl) {
        bilerp2(acc0, u00[pl].x, u01[pl].x, u10[pl].x, u11[pl].x,
                w00[pl], w01[pl], w10[pl], w11[pl]);
        bilerp2(acc1, u00[pl].y, u01[pl].y, u10[pl].y, u11[pl].y,
                w00[pl], w01[pl], w10[pl], w11[pl]);
        bilerp2(acc2, u00[pl].z, u01[pl].z, u10[pl].z, u11[pl].z,
                w00[pl], w01[pl], w10[pl], w11[pl]);
        bilerp2(acc3, u00[pl].w, u01[pl].w, u10[pl].w, u11[pl].w,
                w00[pl], w01[pl], w10[pl], w11[pl]);
    }

    float* op = out + (size_t)b * NCH + q * 8;
    vfloat4 lo = { acc0.x, acc0.y, acc1.x, acc1.y };
    vfloat4 hi = { acc2.x, acc2.y, acc3.x, acc3.y };
    __builtin_nontemporal_store(lo, (vfloat4*)op);
    __builtin_nontemporal_store(hi, (vfloat4*)(op + 4));
}

// ---------------------------------------------------------------------------
// Fallback if d_ws is too small: sample directly from (C,H,W) fp32.
// ---------------------------------------------------------------------------
__global__ __launch_bounds__(256) void triplane_sample_chw(
    const float* __restrict__ x, const float* __restrict__ p0,
    const float* __restrict__ p1, const float* __restrict__ p2,
    float* __restrict__ out, int npts)
{
    int gid = blockIdx.x * 256 + threadIdx.x;
    int b = gid >> 5;
    int c = gid & 31;
    if (b >= npts) return;

    float c0 = x[b * 3 + 0], c1 = x[b * 3 + 1], c2 = x[b * 3 + 2];
    const float gxs[3] = { c0, c0, c1 };
    const float gys[3] = { c1, c2, c2 };
    const float* planes[3] = { p0, p1, p2 };

    float acc = 1.f;
    #pragma unroll
    for (int pl = 0; pl < 3; ++pl) {
        float ix = fmaf(gxs[pl], 255.5f, 255.5f);
        float iy = fmaf(gys[pl], 255.5f, 255.5f);
        float xf = floorf(ix), yf = floorf(iy);
        float wx = ix - xf,  wy = iy - yf;
        int x0 = min(max((int)xf, 0), RES - 2);
        int y0 = min(max((int)yf, 0), RES - 2);

        const float* base = planes[pl] + (size_t)c * HW + (size_t)y0 * RES + x0;
        float v00 = base[0], v01 = base[1], v10 = base[RES], v11 = base[RES + 1];

        float omx = 1.f - wx, omy = 1.f - wy;
        acc *= fmaf(v00, omx * omy, fmaf(v01, wx * omy,
               fmaf(v10, omx * wy, v11 * (wx * wy))));
    }
    out[(size_t)b * NCH + c] = acc;
}

extern "C" void kernel_launch(void* const* d_in, const int* in_sizes, int n_in,
                              void* d_out, int out_size, void* d_ws, size_t ws_size,
                              hipStream_t stream) {
    const float* x  = (const float*)d_in[0];
    const float* p0 = (const float*)d_in[1];
    const float* p1 = (const float*)d_in[2];
    const float* p2 = (const float*)d_in[3];
    float* out = (float*)d_out;
    int npts = in_sizes[0] / 3;

    // workspace layout
    size_t planes_bytes = (size_t)3 * PLANE_H_ELEMS * sizeof(__half);   // 50.3 MB
    size_t sorted_bytes = (size_t)npts * sizeof(float4);                // 32 MB
    size_t hist_bytes   = NBUCKETS * sizeof(unsigned);
    size_t need = planes_bytes + sorted_bytes + 2 * hist_bytes;

    if (ws_size >= need) {
        char* ws = (char*)d_ws;
        __half*   planes_h = (__half*)ws;
        float4*   sorted   = (float4*)(ws + planes_bytes);
        unsigned* hist     = (unsigned*)(ws + planes_bytes + sorted_bytes);
        unsigned* offs     = hist + NBUCKETS;

        transpose_chw_hwc_h<<<3 * 4096, 256, 0, stream>>>(p0, p1, p2,
                                                          (__half2*)planes_h, hist);
        hist_kernel<<<1024, 256, 0, stream>>>(x, npts, hist);
        scan_kernel<<<1, 1024, 0, stream>>>(hist, offs);
        scatter_kernel<<<(npts + 255) / 256, 256, 0, stream>>>(x, npts, offs, sorted);

        int nchunks = (npts + 63) / 64;       // 64 points per block
        int nb_q = nchunks / 8, nb_r = nchunks & 7;
        sample_sorted_u4<<<nchunks, 256, 0, stream>>>(sorted, planes_h, out, npts, nb_q, nb_r);
    } else {
        long long nthreads = (long long)npts * 32;
        int blocks = (int)((nthreads + 255) / 256);
        triplane_sample_chw<<<blocks, 256, 0, stream>>>(x, p0, p1, p2, out, npts);
    }
}